// Round 11
// baseline (124.303 us; speedup 1.0000x reference)
//
#include <hip/hip_runtime.h>

// Problem constants
#define DIM 128
#define HID 256
#define K2LE 2.885390081777927f   // 2*log2(e): tanh(x) = 1 - 2/(exp2(K2LE*x)+1)
#define NTILES 16                 // HID / 16
#define RNPAD 136                 // rnbf row stride (bf16 elems)
#define GXPAD 260                 // g_x row stride (f32)

typedef __attribute__((ext_vector_type(8))) short bf16x8;   // 8 bf16 = 4 VGPRs
typedef __attribute__((ext_vector_type(4))) float f32x4;

__device__ __forceinline__ unsigned short f2bf(float f) {
    union { float f; unsigned u; } x; x.f = f;
    unsigned r = x.u + 0x7fffu + ((x.u >> 16) & 1u);   // RNE
    return (unsigned short)(r >> 16);
}

__device__ __forceinline__ float sigmoid_fast(float x) {
    float t = __builtin_amdgcn_exp2f(-x * 1.4426950408889634f);
    return __builtin_amdgcn_rcpf(1.0f + t);
}

// All-reduce sum across a 16-lane DPP row — VALU pipe only, no LDS.
__device__ __forceinline__ float row16_allreduce(float x) {
    int t;
    t = __builtin_amdgcn_update_dpp(0, __float_as_int(x), 0xB1, 0xf, 0xf, true);
    x += __int_as_float(t);
    t = __builtin_amdgcn_update_dpp(0, __float_as_int(x), 0x4E, 0xf, 0xf, true);
    x += __int_as_float(t);
    t = __builtin_amdgcn_update_dpp(0, __float_as_int(x), 0x124, 0xf, 0xf, true);
    x += __int_as_float(t);
    t = __builtin_amdgcn_update_dpp(0, __float_as_int(x), 0x128, 0xf, 0xf, true);
    x += __int_as_float(t);
    return x;
}

// ---------------------------------------------------------------------------
// Prep (16 blocks x 256):
//   block 0: c2p/w2p[(col&15)*16 + (col>>4)] = K2LE*(pivot@W1+b1)[col], w2[col]
//   all:     W1f = bf16(K2LE*W1) in MFMA B-frag order
// ---------------------------------------------------------------------------
__global__ void k_prep(const float* __restrict__ pivot,
                       const float* __restrict__ W1,
                       const float* __restrict__ b1,
                       const float* __restrict__ w2,
                       float* __restrict__ c2p,
                       float* __restrict__ w2p,
                       uint4* __restrict__ W1f) {
    const int tid = threadIdx.x;
    if (blockIdx.x == 0) {
        float a = b1[tid];
#pragma unroll 8
        for (int d = 0; d < DIM; ++d) a = fmaf(pivot[d], W1[d * HID + tid], a);
        const int pidx = (tid & 15) * 16 + (tid >> 4);   // col -> [m][i]
        c2p[pidx] = K2LE * a;
        w2p[pidx] = w2[tid];
    }
    const int e  = blockIdx.x * 256 + tid;
    const int m  = e & 15;
    const int q  = (e >> 4) & 3;
    const int kk = (e >> 6) & 3;
    const int nt = e >> 8;
    const int n  = nt * 16 + m;
    const int k0 = kk * 32 + q * 8;
    unsigned w[4];
#pragma unroll
    for (int p = 0; p < 4; ++p) {
        unsigned lo = f2bf(W1[(k0 + 2 * p    ) * HID + n] * K2LE);
        unsigned hi = f2bf(W1[(k0 + 2 * p + 1) * HID + n] * K2LE);
        w[p] = lo | (hi << 16);
    }
    W1f[e] = make_uint4(w[0], w[1], w[2], w[3]);
}

// ---------------------------------------------------------------------------
// Fused main: 2048 blocks x 256 thr, 16 rays/block.  (R9 structure + pins)
//  phase 1: lane(q,m) of wave w normalizes ray w*4+q; f32 dir kept in regs
//  phase 2: wave w MFMAs nt-group {4w..4w+3} for all 16 rays; D -> padded LDS
//  phase 3: g/c/w loaded ONCE and pinned in VGPRs via empty asm (prevents the
//           compiler sinking the loads into the loop — R9's VGPR=36 proved it
//           was re-loading all 48 values every iteration); quad-rcp sigmoid;
//           DPP row16 reduce; zero LDS in the loop
//  phase 4: epilogue from f32 regs (no LDS)
// ---------------------------------------------------------------------------
__global__ __launch_bounds__(256, 4) void k_main(
    const float* __restrict__ r,      // [B,128]
    const float* __restrict__ s,      // [B]
    const float* __restrict__ pivot,  // [128]
    const float* __restrict__ c2p,    // [256] permuted K2LE*(pivot@W1+b1)
    const float* __restrict__ w2p,    // [256] permuted w2
    const float* __restrict__ b2,     // [1]
    const int* __restrict__ n_iter_p, // [1]
    const uint4* __restrict__ W1f,    // frag-ordered bf16 K2LE*W1
    float* __restrict__ out)          // [B,128]
{
    __shared__ unsigned short rnbf[16][RNPAD];  // 4.25 KB [ray][k] bf16, padded
    __shared__ float g_x[16][GXPAD];            // 16.25 KB [ray][col] f32, padded

    const int tid   = threadIdx.x;
    const int lane  = tid & 63;
    const int wave  = tid >> 6;        // 0..3: nt-group AND ray-group
    const int m     = lane & 15;
    const int q     = lane >> 4;
    const int ray_l = wave * 4 + q;    // this lane's ray (phases 1,3,4)
    const int ray_g = blockIdx.x * 16 + ray_l;
    const int n_iter = *n_iter_p;

    // ---- Phase 1: load r; keep f32 dir in regs; bf16 copy to LDS for MFMA ----
    float4 v0 = *(const float4*)&r[ray_g * DIM + m * 8];
    float4 v1 = *(const float4*)&r[ray_g * DIM + m * 8 + 4];
    const float sv  = s[ray_g];
    const float b2v = b2[0];

    float ss = v0.x*v0.x + v0.y*v0.y + v0.z*v0.z + v0.w*v0.w
             + v1.x*v1.x + v1.y*v1.y + v1.z*v1.z + v1.w*v1.w;
    ss = row16_allreduce(ss);
    const float inv = __builtin_amdgcn_rsqf(ss);
    unsigned p0 = (unsigned)f2bf(v0.x*inv) | ((unsigned)f2bf(v0.y*inv) << 16);
    unsigned p1 = (unsigned)f2bf(v0.z*inv) | ((unsigned)f2bf(v0.w*inv) << 16);
    unsigned p2 = (unsigned)f2bf(v1.x*inv) | ((unsigned)f2bf(v1.y*inv) << 16);
    unsigned p3 = (unsigned)f2bf(v1.z*inv) | ((unsigned)f2bf(v1.w*inv) << 16);
    *(uint4*)&rnbf[ray_l][m * 8] = make_uint4(p0, p1, p2, p3);
    __syncthreads();

    // ---- Phase 2: wave w computes nt = 4w..4w+3 for all 16 rays ----
    bf16x8 afrag[4];
#pragma unroll
    for (int kk = 0; kk < 4; ++kk)
        afrag[kk] = *(const bf16x8*)&rnbf[m][kk * 32 + q * 8];

    const bf16x8* __restrict__ wf = (const bf16x8*)W1f;
    const int fb = q * 16 + m;
#pragma unroll
    for (int t = 0; t < 4; ++t) {
        const int nt = wave * 4 + t;
        f32x4 a = {0.f, 0.f, 0.f, 0.f};
#pragma unroll
        for (int kk = 0; kk < 4; ++kk)
            a = __builtin_amdgcn_mfma_f32_16x16x32_bf16(
                    afrag[kk], wf[nt * 256 + kk * 64 + fb], a, 0, 0, 0);
        // D: row(ray) = q*4+reg, col = nt*16+m  (m89-verified layout)
#pragma unroll
        for (int r4 = 0; r4 < 4; ++r4)
            g_x[q * 4 + r4][nt * 16 + m] = a[r4];
    }
    __syncthreads();

    // ---- Phase 3 setup: load g/c/w ONCE, pin in VGPRs ----
    float g[16], c[16], w[16];
#pragma unroll
    for (int i = 0; i < 16; ++i) g[i] = g_x[ray_l][i * 16 + m];
#pragma unroll
    for (int i = 0; i < 4; ++i) {
        float4 cv = *(const float4*)(c2p + m * 16 + i * 4);
        float4 wv = *(const float4*)(w2p + m * 16 + i * 4);
        c[4*i]=cv.x; c[4*i+1]=cv.y; c[4*i+2]=cv.z; c[4*i+3]=cv.w;
        w[4*i]=wv.x; w[4*i+1]=wv.y; w[4*i+2]=wv.z; w[4*i+3]=wv.w;
    }
#pragma unroll
    for (int i = 0; i < 16; ++i) {
        asm volatile("" : "+v"(g[i]));
        asm volatile("" : "+v"(c[i]));
        asm volatile("" : "+v"(w[i]));
    }

    float S = 0.f;
#pragma unroll
    for (int i = 0; i < 16; ++i) S += w[i];
    S = row16_allreduce(S);
    const float C0 = K2LE * (S + b2v);

    // ---- Phase 3: march. Quad-rcp: one v_rcp per 4 sigmoids. ----
    float alpha = 0.f;
    for (int it = 0; it < n_iter; ++it) {
        float p = 0.f;
#pragma unroll
        for (int qd = 0; qd < 4; ++qd) {
            const int b = qd * 4;
            float A0 = __builtin_amdgcn_exp2f(fmaf(alpha, g[b+0], c[b+0])) + 1.0f;
            float A1 = __builtin_amdgcn_exp2f(fmaf(alpha, g[b+1], c[b+1])) + 1.0f;
            float A2 = __builtin_amdgcn_exp2f(fmaf(alpha, g[b+2], c[b+2])) + 1.0f;
            float A3 = __builtin_amdgcn_exp2f(fmaf(alpha, g[b+3], c[b+3])) + 1.0f;
            float P01 = A0 * A1;
            float P23 = A2 * A3;
            float n01 = fmaf(w[b+0], A1, w[b+1] * A0);
            float n23 = fmaf(w[b+2], A3, w[b+3] * A2);
            float num = fmaf(n01, P23, n23 * P01);
            float den = P01 * P23;
            p = fmaf(num, __builtin_amdgcn_rcpf(den), p);
        }
        p = row16_allreduce(p);
        float v = __builtin_amdgcn_rcpf(
            __builtin_amdgcn_exp2f(fmaf(-2.0f * K2LE, p, C0)) + 1.0f);
        alpha += fmaf(-0.1f, v, 0.1f);
    }

    // ---- Phase 4: out = pivot + sigmoid(s)*alpha*(r*inv) — all f32, no LDS ----
    const float sc = sigmoid_fast(sv) * alpha * inv;
    float4 pv0 = *(const float4*)(pivot + m * 8);
    float4 pv1 = *(const float4*)(pivot + m * 8 + 4);
    float4 o0, o1;
    o0.x = fmaf(sc, v0.x, pv0.x);
    o0.y = fmaf(sc, v0.y, pv0.y);
    o0.z = fmaf(sc, v0.z, pv0.z);
    o0.w = fmaf(sc, v0.w, pv0.w);
    o1.x = fmaf(sc, v1.x, pv1.x);
    o1.y = fmaf(sc, v1.y, pv1.y);
    o1.z = fmaf(sc, v1.z, pv1.z);
    o1.w = fmaf(sc, v1.w, pv1.w);
    *(float4*)(out + ray_g * DIM + m * 8)     = o0;
    *(float4*)(out + ray_g * DIM + m * 8 + 4) = o1;
}

extern "C" void kernel_launch(void* const* d_in, const int* in_sizes, int n_in,
                              void* d_out, int out_size, void* d_ws, size_t ws_size,
                              hipStream_t stream) {
    const float* r      = (const float*)d_in[0];
    const float* s      = (const float*)d_in[1];
    const float* pivot  = (const float*)d_in[2];
    const float* W1     = (const float*)d_in[3];
    const float* b1     = (const float*)d_in[4];
    const float* w2     = (const float*)d_in[5];
    const float* b2     = (const float*)d_in[6];
    const int*   n_iter = (const int*)d_in[7];
    float* out = (float*)d_out;

    const int B = in_sizes[0] / DIM;  // 32768

    char* ws = (char*)d_ws;
    float* c2p = (float*)(ws);             // 1 KB
    float* w2p = (float*)(ws + 1024);      // 1 KB
    uint4* W1f = (uint4*)(ws + 4096);      // 64 KB

    k_prep<<<16, 256, 0, stream>>>(pivot, W1, b1, w2, c2p, w2p, W1f);
    k_main<<<B / 16, 256, 0, stream>>>(r, s, pivot, c2p, w2p, b2, n_iter,
                                       W1f, out);
}

// Round 12
// 120.453 us; speedup vs baseline: 1.0320x; 1.0320x over previous
//
#include <hip/hip_runtime.h>

// Problem constants
#define DIM 128
#define HID 256
#define K2LE 2.885390081777927f   // 2*log2(e): tanh(x) = 1 - 2/(exp2(K2LE*x)+1)
#define NTILES 16                 // HID / 16
#define RNPAD 136                 // rnbf row stride (bf16 elems)
#define GXPAD 260                 // g_x row stride (f32)

typedef __attribute__((ext_vector_type(8))) short bf16x8;   // 8 bf16 = 4 VGPRs
typedef __attribute__((ext_vector_type(4))) float f32x4;
typedef __attribute__((ext_vector_type(2))) float f32x2;    // -> v_pk_* f32

__device__ __forceinline__ unsigned short f2bf(float f) {
    union { float f; unsigned u; } x; x.f = f;
    unsigned r = x.u + 0x7fffu + ((x.u >> 16) & 1u);   // RNE
    return (unsigned short)(r >> 16);
}

__device__ __forceinline__ float sigmoid_fast(float x) {
    float t = __builtin_amdgcn_exp2f(-x * 1.4426950408889634f);
    return __builtin_amdgcn_rcpf(1.0f + t);
}

// All-reduce sum across a 16-lane DPP row — VALU pipe only, no LDS.
__device__ __forceinline__ float row16_allreduce(float x) {
    int t;
    t = __builtin_amdgcn_update_dpp(0, __float_as_int(x), 0xB1, 0xf, 0xf, true);
    x += __int_as_float(t);
    t = __builtin_amdgcn_update_dpp(0, __float_as_int(x), 0x4E, 0xf, 0xf, true);
    x += __int_as_float(t);
    t = __builtin_amdgcn_update_dpp(0, __float_as_int(x), 0x124, 0xf, 0xf, true);
    x += __int_as_float(t);
    t = __builtin_amdgcn_update_dpp(0, __float_as_int(x), 0x128, 0xf, 0xf, true);
    x += __int_as_float(t);
    return x;
}

// ---------------------------------------------------------------------------
// Prep (16 blocks x 256):
//   block 0: c2p/w2p[(col&15)*16 + (col>>4)] = K2LE*(pivot@W1+b1)[col], w2[col]
//   all:     W1f = bf16(K2LE*W1) in MFMA B-frag order
// ---------------------------------------------------------------------------
__global__ void k_prep(const float* __restrict__ pivot,
                       const float* __restrict__ W1,
                       const float* __restrict__ b1,
                       const float* __restrict__ w2,
                       float* __restrict__ c2p,
                       float* __restrict__ w2p,
                       uint4* __restrict__ W1f) {
    const int tid = threadIdx.x;
    if (blockIdx.x == 0) {
        float a = b1[tid];
#pragma unroll 8
        for (int d = 0; d < DIM; ++d) a = fmaf(pivot[d], W1[d * HID + tid], a);
        const int pidx = (tid & 15) * 16 + (tid >> 4);   // col -> [m][i]
        c2p[pidx] = K2LE * a;
        w2p[pidx] = w2[tid];
    }
    const int e  = blockIdx.x * 256 + tid;
    const int m  = e & 15;
    const int q  = (e >> 4) & 3;
    const int kk = (e >> 6) & 3;
    const int nt = e >> 8;
    const int n  = nt * 16 + m;
    const int k0 = kk * 32 + q * 8;
    unsigned w[4];
#pragma unroll
    for (int p = 0; p < 4; ++p) {
        unsigned lo = f2bf(W1[(k0 + 2 * p    ) * HID + n] * K2LE);
        unsigned hi = f2bf(W1[(k0 + 2 * p + 1) * HID + n] * K2LE);
        w[p] = lo | (hi << 16);
    }
    W1f[e] = make_uint4(w[0], w[1], w[2], w[3]);
}

// ---------------------------------------------------------------------------
// Fused main: 2048 blocks x 256 thr, 16 rays/block.  (R11 structure, packed)
//  phase 1: lane(q,m) of wave w normalizes ray w*4+q; f32 dir kept in regs
//  phase 2: wave w MFMAs nt-group {4w..4w+3} for all 16 rays; D -> padded LDS
//  phase 3: quad-rcp sigmoid with f32x2 packed args (+v_pk_fma_f32 /
//           v_pk_add_f32); DPP row16 reduce; zero LDS in the loop
//  phase 4: epilogue from f32 regs (no LDS)
// ---------------------------------------------------------------------------
__global__ __launch_bounds__(256, 8) void k_main(
    const float* __restrict__ r,      // [B,128]
    const float* __restrict__ s,      // [B]
    const float* __restrict__ pivot,  // [128]
    const float* __restrict__ c2p,    // [256] permuted K2LE*(pivot@W1+b1)
    const float* __restrict__ w2p,    // [256] permuted w2
    const float* __restrict__ b2,     // [1]
    const int* __restrict__ n_iter_p, // [1]
    const uint4* __restrict__ W1f,    // frag-ordered bf16 K2LE*W1
    float* __restrict__ out)          // [B,128]
{
    __shared__ unsigned short rnbf[16][RNPAD];  // 4.25 KB [ray][k] bf16, padded
    __shared__ float g_x[16][GXPAD];            // 16.25 KB [ray][col] f32, padded

    const int tid   = threadIdx.x;
    const int lane  = tid & 63;
    const int wave  = tid >> 6;        // 0..3: nt-group AND ray-group
    const int m     = lane & 15;
    const int q     = lane >> 4;
    const int ray_l = wave * 4 + q;    // this lane's ray (phases 1,3,4)
    const int ray_g = blockIdx.x * 16 + ray_l;
    const int n_iter = *n_iter_p;

    // ---- Phase 1: load r; keep f32 dir in regs; bf16 copy to LDS for MFMA ----
    float4 v0 = *(const float4*)&r[ray_g * DIM + m * 8];
    float4 v1 = *(const float4*)&r[ray_g * DIM + m * 8 + 4];
    const float sv  = s[ray_g];
    const float b2v = b2[0];

    float ss = v0.x*v0.x + v0.y*v0.y + v0.z*v0.z + v0.w*v0.w
             + v1.x*v1.x + v1.y*v1.y + v1.z*v1.z + v1.w*v1.w;
    ss = row16_allreduce(ss);
    const float inv = __builtin_amdgcn_rsqf(ss);
    unsigned p0 = (unsigned)f2bf(v0.x*inv) | ((unsigned)f2bf(v0.y*inv) << 16);
    unsigned p1 = (unsigned)f2bf(v0.z*inv) | ((unsigned)f2bf(v0.w*inv) << 16);
    unsigned p2 = (unsigned)f2bf(v1.x*inv) | ((unsigned)f2bf(v1.y*inv) << 16);
    unsigned p3 = (unsigned)f2bf(v1.z*inv) | ((unsigned)f2bf(v1.w*inv) << 16);
    *(uint4*)&rnbf[ray_l][m * 8] = make_uint4(p0, p1, p2, p3);
    __syncthreads();

    // ---- Phase 2: wave w computes nt = 4w..4w+3 for all 16 rays ----
    bf16x8 afrag[4];
#pragma unroll
    for (int kk = 0; kk < 4; ++kk)
        afrag[kk] = *(const bf16x8*)&rnbf[m][kk * 32 + q * 8];

    const bf16x8* __restrict__ wf = (const bf16x8*)W1f;
    const int fb = q * 16 + m;
#pragma unroll
    for (int t = 0; t < 4; ++t) {
        const int nt = wave * 4 + t;
        f32x4 a = {0.f, 0.f, 0.f, 0.f};
#pragma unroll
        for (int kk = 0; kk < 4; ++kk)
            a = __builtin_amdgcn_mfma_f32_16x16x32_bf16(
                    afrag[kk], wf[nt * 256 + kk * 64 + fb], a, 0, 0, 0);
        // D: row(ray) = q*4+reg, col = nt*16+m  (m89-verified layout)
#pragma unroll
        for (int r4 = 0; r4 < 4; ++r4)
            g_x[q * 4 + r4][nt * 16 + m] = a[r4];
    }
    __syncthreads();

    // ---- Phase 3 setup: lane's 16 cols {i*16+m}, packed into f32x2 pairs ----
    f32x2 g2[8], c2[8];
    float w[16];
#pragma unroll
    for (int j = 0; j < 8; ++j) {
        g2[j].x = g_x[ray_l][(2 * j    ) * 16 + m];
        g2[j].y = g_x[ray_l][(2 * j + 1) * 16 + m];
    }
#pragma unroll
    for (int i = 0; i < 4; ++i) {
        float4 cv = *(const float4*)(c2p + m * 16 + i * 4);
        float4 wv = *(const float4*)(w2p + m * 16 + i * 4);
        c2[2*i]   = (f32x2){cv.x, cv.y};
        c2[2*i+1] = (f32x2){cv.z, cv.w};
        w[4*i]=wv.x; w[4*i+1]=wv.y; w[4*i+2]=wv.z; w[4*i+3]=wv.w;
    }

    float S = 0.f;
#pragma unroll
    for (int i = 0; i < 16; ++i) S += w[i];
    S = row16_allreduce(S);
    const float C0 = K2LE * (S + b2v);

    // ---- Phase 3: march. Quad-rcp + packed args: one v_rcp per 4 sigmoids,
    //      arg compute and +1.0 as f32x2 (v_pk_fma_f32 / v_pk_add_f32). ----
    float alpha = 0.f;
    for (int it = 0; it < n_iter; ++it) {
        const f32x2 alpha2 = {alpha, alpha};
        float p = 0.f;
#pragma unroll
        for (int qd = 0; qd < 4; ++qd) {
            const int b = qd * 4;
            f32x2 arg01 = alpha2 * g2[2*qd]   + c2[2*qd];     // pk_fma
            f32x2 arg23 = alpha2 * g2[2*qd+1] + c2[2*qd+1];   // pk_fma
            f32x2 A01, A23;
            A01.x = __builtin_amdgcn_exp2f(arg01.x);
            A01.y = __builtin_amdgcn_exp2f(arg01.y);
            A23.x = __builtin_amdgcn_exp2f(arg23.x);
            A23.y = __builtin_amdgcn_exp2f(arg23.y);
            A01 += (f32x2){1.0f, 1.0f};                       // pk_add
            A23 += (f32x2){1.0f, 1.0f};                       // pk_add
            float P01 = A01.x * A01.y;
            float P23 = A23.x * A23.y;
            float n01 = fmaf(w[b+0], A01.y, w[b+1] * A01.x);
            float n23 = fmaf(w[b+2], A23.y, w[b+3] * A23.x);
            float num = fmaf(n01, P23, n23 * P01);
            float den = P01 * P23;
            p = fmaf(num, __builtin_amdgcn_rcpf(den), p);
        }
        p = row16_allreduce(p);
        float v = __builtin_amdgcn_rcpf(
            __builtin_amdgcn_exp2f(fmaf(-2.0f * K2LE, p, C0)) + 1.0f);
        alpha += fmaf(-0.1f, v, 0.1f);
    }

    // ---- Phase 4: out = pivot + sigmoid(s)*alpha*(r*inv) — all f32, no LDS ----
    const float sc = sigmoid_fast(sv) * alpha * inv;
    float4 pv0 = *(const float4*)(pivot + m * 8);
    float4 pv1 = *(const float4*)(pivot + m * 8 + 4);
    float4 o0, o1;
    o0.x = fmaf(sc, v0.x, pv0.x);
    o0.y = fmaf(sc, v0.y, pv0.y);
    o0.z = fmaf(sc, v0.z, pv0.z);
    o0.w = fmaf(sc, v0.w, pv0.w);
    o1.x = fmaf(sc, v1.x, pv1.x);
    o1.y = fmaf(sc, v1.y, pv1.y);
    o1.z = fmaf(sc, v1.z, pv1.z);
    o1.w = fmaf(sc, v1.w, pv1.w);
    *(float4*)(out + ray_g * DIM + m * 8)     = o0;
    *(float4*)(out + ray_g * DIM + m * 8 + 4) = o1;
}

extern "C" void kernel_launch(void* const* d_in, const int* in_sizes, int n_in,
                              void* d_out, int out_size, void* d_ws, size_t ws_size,
                              hipStream_t stream) {
    const float* r      = (const float*)d_in[0];
    const float* s      = (const float*)d_in[1];
    const float* pivot  = (const float*)d_in[2];
    const float* W1     = (const float*)d_in[3];
    const float* b1     = (const float*)d_in[4];
    const float* w2     = (const float*)d_in[5];
    const float* b2     = (const float*)d_in[6];
    const int*   n_iter = (const int*)d_in[7];
    float* out = (float*)d_out;

    const int B = in_sizes[0] / DIM;  // 32768

    char* ws = (char*)d_ws;
    float* c2p = (float*)(ws);             // 1 KB
    float* w2p = (float*)(ws + 1024);      // 1 KB
    uint4* W1f = (uint4*)(ws + 4096);      // 64 KB

    k_prep<<<16, 256, 0, stream>>>(pivot, W1, b1, w2, c2p, w2p, W1f);
    k_main<<<B / 16, 256, 0, stream>>>(r, s, pivot, c2p, w2p, b2, n_iter,
                                       W1f, out);
}